// Round 8
// baseline (583.484 us; speedup 1.0000x reference)
//
#include <hip/hip_runtime.h>
#include <hip/hip_bf16.h>
#include <cstdint>
#include <cstddef>

#define D_MODEL 1024
#define SEQ     2048
#define NTOK    4096   // B*S
#define NH      16
#define HD      64

typedef __attribute__((ext_vector_type(8))) short sh8;
typedef __attribute__((ext_vector_type(4))) float f32x4;

#define GLL(g, s) __builtin_amdgcn_global_load_lds(                                   \
    (const __attribute__((address_space(1))) void*)(g),                               \
    (__attribute__((address_space(3))) void*)(s), 16, 0, 0)

__device__ __forceinline__ unsigned short f2b(float f) {
  union { float f; unsigned u; } v; v.f = f;
  unsigned r = v.u + 0x7FFFu + ((v.u >> 16) & 1u);
  return (unsigned short)(r >> 16);
}
__device__ __forceinline__ float b2f(unsigned short h) {
  union { unsigned u; float f; } v; v.u = ((unsigned)h) << 16;
  return v.f;
}

// ---------------- fused fp32 -> bf16 cast for all 6 weights ----------------
__global__ __launch_bounds__(256) void cast6_kernel(
    const float* __restrict__ q, const float* __restrict__ k, const float* __restrict__ v,
    const float* __restrict__ o, const float* __restrict__ u, const float* __restrict__ d,
    unsigned short* __restrict__ oq, unsigned short* __restrict__ ok,
    unsigned short* __restrict__ ov, unsigned short* __restrict__ oo,
    unsigned short* __restrict__ ou, unsigned short* __restrict__ od) {
  int bid = blockIdx.x;
  const float* src; unsigned short* dst; int base;
  if      (bid < 1024) { src = q; dst = oq; base = bid; }
  else if (bid < 2048) { src = k; dst = ok; base = bid - 1024; }
  else if (bid < 3072) { src = v; dst = ov; base = bid - 2048; }
  else if (bid < 4096) { src = o; dst = oo; base = bid - 3072; }
  else if (bid < 8192) { src = u; dst = ou; base = bid - 4096; }
  else                 { src = d; dst = od; base = bid - 8192; }
  int i = base * 1024 + threadIdx.x * 4;
  float4 vv = *(const float4*)(src + i);
  ushort4 w;
  w.x = f2b(vv.x); w.y = f2b(vv.y); w.z = f2b(vv.z); w.w = f2b(vv.w);
  *(ushort4*)(dst + i) = w;
}

// ---------------- LayerNorm (torch var ddof=1), bf16 out ----------------
__global__ __launch_bounds__(256) void ln_kernel(const float* __restrict__ x,
                                                 const float* __restrict__ msc,
                                                 const float* __restrict__ ssc,
                                                 unsigned short* __restrict__ out) {
  const int t = blockIdx.x;
  const int tid = threadIdx.x;
  const float4 v = ((const float4*)(x + (size_t)t * D_MODEL))[tid];
  float s = v.x + v.y + v.z + v.w;
  float q = v.x * v.x + v.y * v.y + v.z * v.z + v.w * v.w;
  #pragma unroll
  for (int off = 32; off; off >>= 1) {
    s += __shfl_xor(s, off);
    q += __shfl_xor(q, off);
  }
  __shared__ float sh[8];
  const int w = tid >> 6;
  if ((tid & 63) == 0) { sh[w * 2] = s; sh[w * 2 + 1] = q; }
  __syncthreads();
  s = sh[0] + sh[2] + sh[4] + sh[6];
  q = sh[1] + sh[3] + sh[5] + sh[7];
  const float mean = s * (1.0f / D_MODEL);
  const float var = (q - (float)D_MODEL * mean * mean) * (1.0f / (D_MODEL - 1));
  const float rstd = rsqrtf(var + 1e-9f);
  const float4 ms = ((const float4*)msc)[tid];
  const float4 ss = ((const float4*)ssc)[tid];
  ushort4 o;
  o.x = f2b((v.x - mean) * rstd * ss.x + ms.x);
  o.y = f2b((v.y - mean) * rstd * ss.y + ms.y);
  o.z = f2b((v.z - mean) * rstd * ss.z + ms.z);
  o.w = f2b((v.w - mean) * rstd * ss.w + ms.w);
  ((ushort4*)(out + (size_t)t * D_MODEL))[tid] = o;
}

// ---------------- split-K partial reduce: out = (x | out) + p0 + p1 -------------
template <bool WITH_X>
__global__ __launch_bounds__(256) void reduce2_kernel(const unsigned short* __restrict__ p0,
                                                      const unsigned short* __restrict__ p1,
                                                      const float* __restrict__ x,
                                                      float* __restrict__ out) {
  int i = (blockIdx.x * 256 + threadIdx.x) * 4;
  ushort4 a = *(const ushort4*)(p0 + i);
  ushort4 b = *(const ushort4*)(p1 + i);
  float4 base = WITH_X ? *(const float4*)(x + i) : *(const float4*)(out + i);
  float4 r;
  r.x = base.x + b2f(a.x) + b2f(b.x);
  r.y = base.y + b2f(a.y) + b2f(b.y);
  r.z = base.z + b2f(a.z) + b2f(b.z);
  r.w = base.w + b2f(a.w) + b2f(b.w);
  *(float4*)(out + i) = r;
}

// ---------------- V transpose: qkv[tok][2048+d] -> vt[b][d][s] ----------------
__global__ __launch_bounds__(256) void vtrans_kernel(const unsigned short* __restrict__ qkv,
                                                     unsigned short* __restrict__ vt) {
  __shared__ unsigned short T[64][72];
  const int st = blockIdx.x;            // s-tile 0..31
  const int b  = blockIdx.y >> 4;
  const int dt = blockIdx.y & 15;       // d-tile 0..15
  const int tid = threadIdx.x;
  const int s0 = st * 64, d0 = dt * 64;
  const int r = tid >> 2, c0 = (tid & 3) * 16;
  const unsigned short* src = qkv + ((size_t)b * SEQ + s0 + r) * 3072 + 2 * D_MODEL + d0 + c0;
  *(uint4*)&T[r][c0]     = *(const uint4*)(src);
  *(uint4*)&T[r][c0 + 8] = *(const uint4*)(src + 8);
  __syncthreads();
  unsigned short buf[16] __attribute__((aligned(16)));
  #pragma unroll
  for (int j = 0; j < 16; j++) buf[j] = T[c0 + j][r];
  unsigned short* dst = vt + ((size_t)b * D_MODEL + d0 + r) * SEQ + s0 + c0;
  *(uint4*)(dst)     = *(uint4*)&buf[0];
  *(uint4*)(dst + 8) = *(uint4*)&buf[8];
}

// ---------------- NT GEMM, BK=64, XOR-swizzled LDS, split-K via 2 out ptrs -----
template <int EP>
__global__ __launch_bounds__(256) void gemm_nt(const unsigned short* __restrict__ A,
                                               const unsigned short* __restrict__ B,
                                               int N, int LD, int Kext,
                                               unsigned short* __restrict__ Cbf,
                                               unsigned short* __restrict__ Cbf2) {
  __shared__ __align__(16) unsigned short As[128 * 64];
  __shared__ __align__(16) unsigned short Bs[128 * 64];
  const int tid = threadIdx.x;
  const int w = tid >> 6, l = tid & 63, ln = tid & 15, quad = (tid & 63) >> 4;
  const int wr = (w >> 1) * 64, wc = (w & 1) * 64;
  const int m0 = blockIdx.y * 128, n0 = blockIdx.x * 128;
  const int koff = blockIdx.z * Kext;

  const int sr = l >> 3, sc = l & 7;
  const unsigned short* AgS = A + (size_t)(m0 + w * 32 + sr) * LD + koff + ((sc ^ sr) * 8);
  const unsigned short* BgS = B + (size_t)(n0 + w * 32 + sr) * LD + koff + ((sc ^ sr) * 8);
  unsigned short* AsW = &As[(w * 32) * 64];
  unsigned short* BsW = &Bs[(w * 32) * 64];

  f32x4 acc[4][4] = {};

  for (int k0 = 0; k0 < Kext; k0 += 64) {
    __syncthreads();
    #pragma unroll
    for (int off = 0; off < 32; off += 8) {
      GLL(AgS + k0 + (size_t)off * LD, AsW + off * 64);
      GLL(BgS + k0 + (size_t)off * LD, BsW + off * 64);
    }
    __syncthreads();
    sh8 af[2][4], bfr[2][4];
    #pragma unroll
    for (int kk = 0; kk < 2; kk++) {
      #pragma unroll
      for (int i = 0; i < 4; i++)
        af[kk][i]  = *(const sh8*)&As[(wr + i * 16 + ln) * 64 + (((kk * 4 + quad) ^ (ln & 7)) * 8)];
      #pragma unroll
      for (int j = 0; j < 4; j++)
        bfr[kk][j] = *(const sh8*)&Bs[(wc + j * 16 + ln) * 64 + (((kk * 4 + quad) ^ (ln & 7)) * 8)];
    }
    #pragma unroll
    for (int kk = 0; kk < 2; kk++)
      #pragma unroll
      for (int i = 0; i < 4; i++)
        #pragma unroll
        for (int j = 0; j < 4; j++)
          acc[i][j] = __builtin_amdgcn_mfma_f32_16x16x32_bf16(af[kk][i], bfr[kk][j], acc[i][j], 0, 0, 0);
  }

  unsigned short* C = blockIdx.z ? Cbf2 : Cbf;
  #pragma unroll
  for (int i = 0; i < 4; i++) {
    #pragma unroll
    for (int rr = 0; rr < 4; rr++) {
      const int gm = m0 + wr + i * 16 + quad * 4 + rr;
      #pragma unroll
      for (int j = 0; j < 4; j++) {
        const int gn = n0 + wc + j * 16 + ln;
        const float v = acc[i][j][rr];
        const size_t idx = (size_t)gm * N + gn;
        if (EP == 0) {
          C[idx] = f2b(v);
        } else {
          const float g = 0.5f * v * (1.0f + erff(v * 0.70710678118654752f));
          C[idx] = f2b(g);
        }
      }
    }
  }
}

// ---------------- Wave-level flash attention: NO barriers, NO K/V LDS ---------
// Each wave owns a 16-row q-strip; K/V fragments loaded global->VGPR directly.
// Fixed-max softmax (exp(z/8-4)); per-wave P round-trip through private LDS.
__global__ __launch_bounds__(256) void attn_kernel(const unsigned short* __restrict__ qkv,
                                                   const unsigned short* __restrict__ vt,
                                                   unsigned short* __restrict__ outp) {
  const int tid = threadIdx.x;
  const int w = tid >> 6, ln = tid & 15, quad = (tid & 63) >> 4;
  const int strip = 127 - (blockIdx.x * 4 + w);   // reversed: long strips first
  const int bh = blockIdx.y;
  const int b = bh >> 4, h = bh & 15;

  __shared__ __align__(16) unsigned short Ps[4][16 * 72];
  unsigned short* Psw = &Ps[w][0];

  const size_t rstride = 3 * D_MODEL;
  const unsigned short* Qg = qkv + (size_t)b * SEQ * rstride + h * HD;
  const unsigned short* Kg = Qg + D_MODEL;
  const unsigned short* Vg = vt + ((size_t)b * D_MODEL + h * HD) * SEQ;

  // Q fragment (A layout: m = ln, k = quad*8 + j)
  sh8 qf[2];
  {
    const unsigned short* qrow = Qg + (size_t)(strip * 16 + ln) * rstride + quad * 8;
    qf[0] = *(const sh8*)(qrow);
    qf[1] = *(const sh8*)(qrow + 32);
  }

  f32x4 o[4] = {};
  float lpart[4] = {0.f, 0.f, 0.f, 0.f};
  const int rbase = strip * 16 + quad * 4;
  const int nkt = (strip >> 2) + 1;

  for (int kt = 0; kt < nkt; kt++) {
    const bool diag = (kt == nkt - 1);
    // K fragments (B-operand: k-row = ct*16+ln, chunk quad): 4 quads cover one
    // 64B line per row -> full line utilization
    sh8 kf[4][2], vf[4][2];
    const unsigned short* kbase = Kg + (size_t)(kt * 64 + ln) * rstride + quad * 8;
    #pragma unroll
    for (int ct = 0; ct < 4; ct++) {
      kf[ct][0] = *(const sh8*)(kbase + (size_t)(ct * 16) * rstride);
      kf[ct][1] = *(const sh8*)(kbase + (size_t)(ct * 16) * rstride + 32);
    }
    const unsigned short* vbase = Vg + (size_t)ln * SEQ + kt * 64 + quad * 8;
    #pragma unroll
    for (int c2 = 0; c2 < 4; c2++) {
      vf[c2][0] = *(const sh8*)(vbase + (size_t)(c2 * 16) * SEQ);
      vf[c2][1] = *(const sh8*)(vbase + (size_t)(c2 * 16) * SEQ + 32);
    }

    // S = Q K^T, softmax, P -> per-wave LDS
    #pragma unroll
    for (int ct = 0; ct < 4; ct++) {
      f32x4 zz = {};
      zz = __builtin_amdgcn_mfma_f32_16x16x32_bf16(qf[0], kf[ct][0], zz, 0, 0, 0);
      zz = __builtin_amdgcn_mfma_f32_16x16x32_bf16(qf[1], kf[ct][1], zz, 0, 0, 0);
      const int cg = kt * 64 + ct * 16 + ln;
      #pragma unroll
      for (int rr = 0; rr < 4; rr++) {
        float e = exp2f(fmaf(zz[rr], 0.18033688011112042f, -5.770780163555853f));
        if (diag && cg > rbase + rr) e = 0.0f;
        lpart[rr] += e;
        Psw[(quad * 4 + rr) * 72 + ct * 16 + ln] = f2b(e);
      }
    }

    // O += P V (in-wave LDS write->read; compiler inserts lgkmcnt)
    #pragma unroll
    for (int kk = 0; kk < 2; kk++) {
      sh8 pf = *(const sh8*)&Psw[ln * 72 + kk * 32 + quad * 8];
      #pragma unroll
      for (int c2 = 0; c2 < 4; c2++)
        o[c2] = __builtin_amdgcn_mfma_f32_16x16x32_bf16(pf, vf[c2][kk], o[c2], 0, 0, 0);
    }
  }

  // row-sum reduction within 16-lane groups, then normalized write
  #pragma unroll
  for (int rr = 0; rr < 4; rr++) {
    #pragma unroll
    for (int off = 1; off < 16; off <<= 1) lpart[rr] += __shfl_xor(lpart[rr], off);
  }
  #pragma unroll
  for (int rr = 0; rr < 4; rr++) {
    const int row = strip * 16 + quad * 4 + rr;
    const float inv = 1.0f / lpart[rr];
    const size_t base = ((size_t)b * SEQ + row) * D_MODEL + h * HD;
    #pragma unroll
    for (int c2 = 0; c2 < 4; c2++)
      outp[base + c2 * 16 + ln] = f2b(o[c2][rr] * inv);
  }
}

extern "C" void kernel_launch(void* const* d_in, const int* in_sizes, int n_in,
                              void* d_out, int out_size, void* d_ws, size_t ws_size,
                              hipStream_t stream) {
  const float* x    = (const float*)d_in[0];
  const float* Wq   = (const float*)d_in[1];
  const float* Wk   = (const float*)d_in[2];
  const float* Wv   = (const float*)d_in[3];
  const float* Wo   = (const float*)d_in[4];
  const float* Wup  = (const float*)d_in[5];
  const float* Wdn  = (const float*)d_in[6];
  const float* ln1m = (const float*)d_in[7];
  const float* ln1s = (const float*)d_in[8];
  const float* ln2m = (const float*)d_in[9];
  const float* ln2s = (const float*)d_in[10];
  float* out = (float*)d_out;

  unsigned short* ws = (unsigned short*)d_ws;
  size_t off = 0;
  unsigned short* wqkv = ws + off; off += (size_t)3072 * 1024;
  unsigned short* wo   = ws + off; off += (size_t)1024 * 1024;
  unsigned short* wup  = ws + off; off += (size_t)4096 * 1024;
  unsigned short* wdn  = ws + off; off += (size_t)1024 * 4096;
  unsigned short* xln  = ws + off; off += (size_t)NTOK * 1024;
  unsigned short* qkvb = ws + off; off += (size_t)NTOK * 3072;
  unsigned short* pre  = ws + off; off += (size_t)NTOK * 1024;
  unsigned short* mid  = qkvb;   // up-GEMM out [4096][4096] spans qkvb+pre exactly
  unsigned short* vtg  = xln;    // V^T aliases xln during attention (dead until LN2)
  unsigned short* po0  = qkvb;   // O-proj partials (qkvb dead after attn)
  unsigned short* po1  = qkvb + (size_t)NTOK * 1024;
  unsigned short* pd0  = ws;     // down partial 0: wqkv+wo region (weights dead)
  unsigned short* pd1  = xln;    // down partial 1 (NOT pre: pre aliases mid rows)

  // fused weight casts (12288 blocks x 1024 elems)
  cast6_kernel<<<12288, 256, 0, stream>>>(Wq, Wk, Wv, Wo, Wup, Wdn,
      wqkv, wqkv + (size_t)1024 * 1024, wqkv + (size_t)2 * 1024 * 1024, wo, wup, wdn);

  // LN1
  ln_kernel<<<NTOK, 256, 0, stream>>>(x, ln1m, ln1s, xln);
  // fused QKV projection (wqkv consumed here; its region is scratch afterwards)
  gemm_nt<0><<<dim3(24, 32, 1), 256, 0, stream>>>(xln, wqkv, 3072, 1024, 1024, qkvb, nullptr);
  // V transpose (xln region becomes vtg)
  vtrans_kernel<<<dim3(32, 32), 256, 0, stream>>>(qkvb, vtg);
  // causal flash attention: 4096 independent waves, no barriers
  attn_kernel<<<dim3(32, 2 * NH), 256, 0, stream>>>(qkvb, vtg, pre);
  // O-projection, split-K=2 -> bf16 partials
  gemm_nt<0><<<dim3(8, 32, 2), 256, 0, stream>>>(pre, wo, 1024, 1024, 512, po0, po1);
  // out = x + po0 + po1
  reduce2_kernel<true><<<4096, 256, 0, stream>>>(po0, po1, x, out);
  // LN2
  ln_kernel<<<NTOK, 256, 0, stream>>>(out, ln2m, ln2s, xln);
  // MLP up + exact GELU -> mid
  gemm_nt<2><<<dim3(32, 32, 1), 256, 0, stream>>>(xln, wup, 4096, 1024, 1024, mid, nullptr);
  // MLP down, split-K=2 -> bf16 partials (pd1 = xln, no overlap with mid)
  gemm_nt<0><<<dim3(8, 32, 2), 256, 0, stream>>>(mid, wdn, 1024, 4096, 2048, pd0, pd1);
  // out += pd0 + pd1
  reduce2_kernel<false><<<4096, 256, 0, stream>>>(pd0, pd1, nullptr, out);
}

// Round 9
// 342.084 us; speedup vs baseline: 1.7057x; 1.7057x over previous
//
#include <hip/hip_runtime.h>
#include <hip/hip_bf16.h>
#include <cstdint>
#include <cstddef>

#define D_MODEL 1024
#define SEQ     2048
#define NTOK    4096   // B*S
#define NH      16
#define HD      64

typedef __attribute__((ext_vector_type(8))) short sh8;
typedef __attribute__((ext_vector_type(4))) float f32x4;

#define GLL(g, s) __builtin_amdgcn_global_load_lds(                                   \
    (const __attribute__((address_space(1))) void*)(g),                               \
    (__attribute__((address_space(3))) void*)(s), 16, 0, 0)

__device__ __forceinline__ unsigned short f2b(float f) {
  union { float f; unsigned u; } v; v.f = f;
  unsigned r = v.u + 0x7FFFu + ((v.u >> 16) & 1u);
  return (unsigned short)(r >> 16);
}
__device__ __forceinline__ float b2f(unsigned short h) {
  union { unsigned u; float f; } v; v.u = ((unsigned)h) << 16;
  return v.f;
}

// ---------------- fused fp32 -> bf16 cast for all 6 weights ----------------
__global__ __launch_bounds__(256) void cast6_kernel(
    const float* __restrict__ q, const float* __restrict__ k, const float* __restrict__ v,
    const float* __restrict__ o, const float* __restrict__ u, const float* __restrict__ d,
    unsigned short* __restrict__ oq, unsigned short* __restrict__ ok,
    unsigned short* __restrict__ ov, unsigned short* __restrict__ oo,
    unsigned short* __restrict__ ou, unsigned short* __restrict__ od) {
  int bid = blockIdx.x;
  const float* src; unsigned short* dst; int base;
  if      (bid < 1024) { src = q; dst = oq; base = bid; }
  else if (bid < 2048) { src = k; dst = ok; base = bid - 1024; }
  else if (bid < 3072) { src = v; dst = ov; base = bid - 2048; }
  else if (bid < 4096) { src = o; dst = oo; base = bid - 3072; }
  else if (bid < 8192) { src = u; dst = ou; base = bid - 4096; }
  else                 { src = d; dst = od; base = bid - 8192; }
  int i = base * 1024 + threadIdx.x * 4;
  float4 vv = *(const float4*)(src + i);
  ushort4 w;
  w.x = f2b(vv.x); w.y = f2b(vv.y); w.z = f2b(vv.z); w.w = f2b(vv.w);
  *(ushort4*)(dst + i) = w;
}

// ---------------- LayerNorm (torch var ddof=1), bf16 out ----------------
__global__ __launch_bounds__(256) void ln_kernel(const float* __restrict__ x,
                                                 const float* __restrict__ msc,
                                                 const float* __restrict__ ssc,
                                                 unsigned short* __restrict__ out) {
  const int t = blockIdx.x;
  const int tid = threadIdx.x;
  const float4 v = ((const float4*)(x + (size_t)t * D_MODEL))[tid];
  float s = v.x + v.y + v.z + v.w;
  float q = v.x * v.x + v.y * v.y + v.z * v.z + v.w * v.w;
  #pragma unroll
  for (int off = 32; off; off >>= 1) {
    s += __shfl_xor(s, off);
    q += __shfl_xor(q, off);
  }
  __shared__ float sh[8];
  const int w = tid >> 6;
  if ((tid & 63) == 0) { sh[w * 2] = s; sh[w * 2 + 1] = q; }
  __syncthreads();
  s = sh[0] + sh[2] + sh[4] + sh[6];
  q = sh[1] + sh[3] + sh[5] + sh[7];
  const float mean = s * (1.0f / D_MODEL);
  const float var = (q - (float)D_MODEL * mean * mean) * (1.0f / (D_MODEL - 1));
  const float rstd = rsqrtf(var + 1e-9f);
  const float4 ms = ((const float4*)msc)[tid];
  const float4 ss = ((const float4*)ssc)[tid];
  ushort4 o;
  o.x = f2b((v.x - mean) * rstd * ss.x + ms.x);
  o.y = f2b((v.y - mean) * rstd * ss.y + ms.y);
  o.z = f2b((v.z - mean) * rstd * ss.z + ms.z);
  o.w = f2b((v.w - mean) * rstd * ss.w + ms.w);
  ((ushort4*)(out + (size_t)t * D_MODEL))[tid] = o;
}

// -------- fused: out = x + p0 + p1 ; oln = LN2(out) (one pass per row) --------
__global__ __launch_bounds__(256) void reduce_ln_kernel(
    const unsigned short* __restrict__ p0, const unsigned short* __restrict__ p1,
    const float* __restrict__ x, const float* __restrict__ msc,
    const float* __restrict__ ssc, float* __restrict__ out,
    unsigned short* __restrict__ oln) {
  const int t = blockIdx.x;
  const int tid = threadIdx.x;
  const size_t base = (size_t)t * D_MODEL + tid * 4;
  ushort4 a = *(const ushort4*)(p0 + base);
  ushort4 b = *(const ushort4*)(p1 + base);
  float4 xv = *(const float4*)(x + base);
  float4 r;
  r.x = xv.x + b2f(a.x) + b2f(b.x);
  r.y = xv.y + b2f(a.y) + b2f(b.y);
  r.z = xv.z + b2f(a.z) + b2f(b.z);
  r.w = xv.w + b2f(a.w) + b2f(b.w);
  *(float4*)(out + base) = r;
  float s = r.x + r.y + r.z + r.w;
  float q = r.x * r.x + r.y * r.y + r.z * r.z + r.w * r.w;
  #pragma unroll
  for (int off = 32; off; off >>= 1) {
    s += __shfl_xor(s, off);
    q += __shfl_xor(q, off);
  }
  __shared__ float sh[8];
  const int w = tid >> 6;
  if ((tid & 63) == 0) { sh[w * 2] = s; sh[w * 2 + 1] = q; }
  __syncthreads();
  s = sh[0] + sh[2] + sh[4] + sh[6];
  q = sh[1] + sh[3] + sh[5] + sh[7];
  const float mean = s * (1.0f / D_MODEL);
  const float var = (q - (float)D_MODEL * mean * mean) * (1.0f / (D_MODEL - 1));
  const float rstd = rsqrtf(var + 1e-9f);
  const float4 ms = ((const float4*)msc)[tid];
  const float4 ss = ((const float4*)ssc)[tid];
  ushort4 o;
  o.x = f2b((r.x - mean) * rstd * ss.x + ms.x);
  o.y = f2b((r.y - mean) * rstd * ss.y + ms.y);
  o.z = f2b((r.z - mean) * rstd * ss.z + ms.z);
  o.w = f2b((r.w - mean) * rstd * ss.w + ms.w);
  *(ushort4*)(oln + base) = o;
}

// ---------------- split-K partial reduce: out += p0 + p1 ----------------------
__global__ __launch_bounds__(256) void reduce2_kernel(const unsigned short* __restrict__ p0,
                                                      const unsigned short* __restrict__ p1,
                                                      float* __restrict__ out) {
  int i = (blockIdx.x * 256 + threadIdx.x) * 4;
  ushort4 a = *(const ushort4*)(p0 + i);
  ushort4 b = *(const ushort4*)(p1 + i);
  float4 base = *(const float4*)(out + i);
  float4 r;
  r.x = base.x + b2f(a.x) + b2f(b.x);
  r.y = base.y + b2f(a.y) + b2f(b.y);
  r.z = base.z + b2f(a.z) + b2f(b.z);
  r.w = base.w + b2f(a.w) + b2f(b.w);
  *(float4*)(out + i) = r;
}

// ---------------- attention split-key combine: pre = (p0+p1)/(l0+l1) ----------
__global__ __launch_bounds__(256) void attn_combine_kernel(
    unsigned short* __restrict__ p0, const unsigned short* __restrict__ p1,
    const float* __restrict__ l0, const float* __restrict__ l1) {
  int i = (blockIdx.x * 256 + threadIdx.x) * 4;
  const int tok = i >> 10, ch = i & 1023;
  const int b = tok >> 11, s = tok & 2047, h = ch >> 6;
  const int lidx = ((b << 4) + h) * 2048 + s;
  const float inv = 1.0f / (l0[lidx] + l1[lidx]);
  ushort4 a = *(const ushort4*)(p0 + i);
  ushort4 c = *(const ushort4*)(p1 + i);
  ushort4 r;
  r.x = f2b((b2f(a.x) + b2f(c.x)) * inv);
  r.y = f2b((b2f(a.y) + b2f(c.y)) * inv);
  r.z = f2b((b2f(a.z) + b2f(c.z)) * inv);
  r.w = f2b((b2f(a.w) + b2f(c.w)) * inv);
  *(ushort4*)(p0 + i) = r;
}

// ---------------- V transpose: qkv[tok][2048+d] -> vt[b][d][s] ----------------
__global__ __launch_bounds__(256) void vtrans_kernel(const unsigned short* __restrict__ qkv,
                                                     unsigned short* __restrict__ vt) {
  __shared__ unsigned short T[64][72];
  const int st = blockIdx.x;            // s-tile 0..31
  const int b  = blockIdx.y >> 4;
  const int dt = blockIdx.y & 15;       // d-tile 0..15
  const int tid = threadIdx.x;
  const int s0 = st * 64, d0 = dt * 64;
  const int r = tid >> 2, c0 = (tid & 3) * 16;
  const unsigned short* src = qkv + ((size_t)b * SEQ + s0 + r) * 3072 + 2 * D_MODEL + d0 + c0;
  *(uint4*)&T[r][c0]     = *(const uint4*)(src);
  *(uint4*)&T[r][c0 + 8] = *(const uint4*)(src + 8);
  __syncthreads();
  unsigned short buf[16] __attribute__((aligned(16)));
  #pragma unroll
  for (int j = 0; j < 16; j++) buf[j] = T[c0 + j][r];
  unsigned short* dst = vt + ((size_t)b * D_MODEL + d0 + r) * SEQ + s0 + c0;
  *(uint4*)(dst)     = *(uint4*)&buf[0];
  *(uint4*)(dst + 8) = *(uint4*)&buf[8];
}

// ---------------- NT GEMM, BK=64, XOR-swizzled LDS, split-K via 2 out ptrs -----
template <int EP>
__global__ __launch_bounds__(256) void gemm_nt(const unsigned short* __restrict__ A,
                                               const unsigned short* __restrict__ B,
                                               int N, int LD, int Kext,
                                               unsigned short* __restrict__ Cbf,
                                               unsigned short* __restrict__ Cbf2) {
  __shared__ __align__(16) unsigned short As[128 * 64];
  __shared__ __align__(16) unsigned short Bs[128 * 64];
  const int tid = threadIdx.x;
  const int w = tid >> 6, l = tid & 63, ln = tid & 15, quad = (tid & 63) >> 4;
  const int wr = (w >> 1) * 64, wc = (w & 1) * 64;
  const int m0 = blockIdx.y * 128, n0 = blockIdx.x * 128;
  const int koff = blockIdx.z * Kext;

  const int sr = l >> 3, sc = l & 7;
  const unsigned short* AgS = A + (size_t)(m0 + w * 32 + sr) * LD + koff + ((sc ^ sr) * 8);
  const unsigned short* BgS = B + (size_t)(n0 + w * 32 + sr) * LD + koff + ((sc ^ sr) * 8);
  unsigned short* AsW = &As[(w * 32) * 64];
  unsigned short* BsW = &Bs[(w * 32) * 64];

  f32x4 acc[4][4] = {};

  for (int k0 = 0; k0 < Kext; k0 += 64) {
    __syncthreads();
    #pragma unroll
    for (int off = 0; off < 32; off += 8) {
      GLL(AgS + k0 + (size_t)off * LD, AsW + off * 64);
      GLL(BgS + k0 + (size_t)off * LD, BsW + off * 64);
    }
    __syncthreads();
    sh8 af[2][4], bfr[2][4];
    #pragma unroll
    for (int kk = 0; kk < 2; kk++) {
      #pragma unroll
      for (int i = 0; i < 4; i++)
        af[kk][i]  = *(const sh8*)&As[(wr + i * 16 + ln) * 64 + (((kk * 4 + quad) ^ (ln & 7)) * 8)];
      #pragma unroll
      for (int j = 0; j < 4; j++)
        bfr[kk][j] = *(const sh8*)&Bs[(wc + j * 16 + ln) * 64 + (((kk * 4 + quad) ^ (ln & 7)) * 8)];
    }
    #pragma unroll
    for (int kk = 0; kk < 2; kk++)
      #pragma unroll
      for (int i = 0; i < 4; i++)
        #pragma unroll
        for (int j = 0; j < 4; j++)
          acc[i][j] = __builtin_amdgcn_mfma_f32_16x16x32_bf16(af[kk][i], bfr[kk][j], acc[i][j], 0, 0, 0);
  }

  unsigned short* C = blockIdx.z ? Cbf2 : Cbf;
  #pragma unroll
  for (int i = 0; i < 4; i++) {
    #pragma unroll
    for (int rr = 0; rr < 4; rr++) {
      const int gm = m0 + wr + i * 16 + quad * 4 + rr;
      #pragma unroll
      for (int j = 0; j < 4; j++) {
        const int gn = n0 + wc + j * 16 + ln;
        const float v = acc[i][j][rr];
        const size_t idx = (size_t)gm * N + gn;
        if (EP == 0) {
          C[idx] = f2b(v);
        } else {
          const float g = 0.5f * v * (1.0f + erff(v * 0.70710678118654752f));
          C[idx] = f2b(g);
        }
      }
    }
  }
}

// ---------------- Flash attention, causal, BM=64, BN=64, fixed-max softmax ----
// Split-key parity z; GLL staging (R6 structure — best measured).
// Grid XCD-swizzle: bh = blockIdx.x so all blocks of one bh land on one XCD
// (linear id % 8 == bh % 8): K/V working set (256KB/bh, 4 bh/XCD) fits XCD L2.
__global__ __launch_bounds__(256) void attn_kernel(const unsigned short* __restrict__ qkv,
                                                   const unsigned short* __restrict__ vt,
                                                   unsigned short* __restrict__ p0,
                                                   unsigned short* __restrict__ p1,
                                                   float* __restrict__ l0,
                                                   float* __restrict__ l1) {
  const int bh = blockIdx.x;                    // XCD swizzle: bh fastest
  const int qt = (SEQ / 64 - 1) - blockIdx.y;   // reversed: long blocks first
  const int z  = blockIdx.z;
  const int b = bh >> 4, h = bh & 15;
  const int tid = threadIdx.x;
  const int w = tid >> 6, l = tid & 63, ln = tid & 15, quad = (tid & 63) >> 4;
  const int q0 = qt * 64;

  __shared__ __align__(16) unsigned short Ks[64 * 64];   // [key][d], chunk ^ (key&7)
  __shared__ __align__(16) unsigned short Vs[64 * 64];   // [d][key], chunk ^ (d&7)
  __shared__ __align__(16) unsigned short Ps[4][16 * 72];

  const size_t rstride = 3 * D_MODEL;
  const unsigned short* Qg = qkv + (size_t)b * SEQ * rstride + h * HD;
  const unsigned short* Kg = Qg + D_MODEL;
  const unsigned short* Vg = vt + ((size_t)b * D_MODEL + h * HD) * SEQ;

  sh8 qf[2];
  {
    const unsigned short* qrow = Qg + (size_t)(q0 + w * 16 + ln) * rstride + quad * 8;
    qf[0] = *(const sh8*)(qrow);
    qf[1] = *(const sh8*)(qrow + 32);
  }

  const int lr3 = l >> 3, lp3 = l & 7;
  const int cS = (lp3 ^ lr3) * 8;
  const unsigned short* KgS = Kg + (size_t)(w * 16 + lr3) * rstride + cS;
  unsigned short* KsW = &Ks[(w * 16) * 64];
  const unsigned short* VgS = Vg + (size_t)(w * 16 + lr3) * SEQ + cS;
  unsigned short* VsW = &Vs[(w * 16) * 64];
  unsigned short* Psw = &Ps[w][0];

  f32x4 o[4] = {};
  float lpart[4] = {0.f, 0.f, 0.f, 0.f};
  const int rbase = q0 + w * 16 + quad * 4;

  auto tile = [&](int kt, bool diag) {
    __syncthreads();
    GLL(KgS + (size_t)(kt * 64) * rstride,     KsW);
    GLL(KgS + (size_t)(kt * 64 + 8) * rstride, KsW + 8 * 64);
    GLL(VgS + kt * 64,           VsW);
    GLL(VgS + 8 * SEQ + kt * 64, VsW + 8 * 64);
    __syncthreads();

    #pragma unroll
    for (int ct = 0; ct < 4; ct++) {
      const int k = ct * 16 + ln;
      f32x4 zz = {};
      zz = __builtin_amdgcn_mfma_f32_16x16x32_bf16(
          qf[0], *(const sh8*)&Ks[k * 64 + ((quad ^ (k & 7)) * 8)], zz, 0, 0, 0);
      zz = __builtin_amdgcn_mfma_f32_16x16x32_bf16(
          qf[1], *(const sh8*)&Ks[k * 64 + (((4 + quad) ^ (k & 7)) * 8)], zz, 0, 0, 0);
      const int cg = kt * 64 + ct * 16 + ln;
      #pragma unroll
      for (int rr = 0; rr < 4; rr++) {
        float e = exp2f(fmaf(zz[rr], 0.18033688011112042f, -5.770780163555853f));
        if (diag && cg > rbase + rr) e = 0.0f;
        lpart[rr] += e;
        Psw[(quad * 4 + rr) * 72 + ct * 16 + ln] = f2b(e);
      }
    }

    #pragma unroll
    for (int kk = 0; kk < 2; kk++) {
      sh8 pf = *(const sh8*)&Psw[ln * 72 + kk * 32 + quad * 8];
      #pragma unroll
      for (int c2 = 0; c2 < 4; c2++) {
        const int d = c2 * 16 + ln;
        sh8 vf = *(const sh8*)&Vs[d * 64 + ((((kk * 4 + quad) ^ (d & 7))) * 8)];
        o[c2] = __builtin_amdgcn_mfma_f32_16x16x32_bf16(pf, vf, o[c2], 0, 0, 0);
      }
    }
  };

  // key-tiles of parity z (diagonal tile has parity qt&1)
  for (int kt = z; kt < qt; kt += 2) tile(kt, false);
  if ((qt & 1) == z) tile(qt, true);

  #pragma unroll
  for (int rr = 0; rr < 4; rr++) {
    #pragma unroll
    for (int off = 1; off < 16; off <<= 1) lpart[rr] += __shfl_xor(lpart[rr], off);
  }

  unsigned short* P = z ? p1 : p0;
  float* L = z ? l1 : l0;
  if (ln == 0) {
    #pragma unroll
    for (int rr = 0; rr < 4; rr++)
      L[((size_t)bh << 11) + q0 + w * 16 + quad * 4 + rr] = lpart[rr];
  }
  #pragma unroll
  for (int rr = 0; rr < 4; rr++) {
    const int row = q0 + w * 16 + quad * 4 + rr;
    const size_t base = ((size_t)b * SEQ + row) * D_MODEL + h * HD;
    #pragma unroll
    for (int c2 = 0; c2 < 4; c2++)
      P[base + c2 * 16 + ln] = f2b(o[c2][rr]);
  }
}

extern "C" void kernel_launch(void* const* d_in, const int* in_sizes, int n_in,
                              void* d_out, int out_size, void* d_ws, size_t ws_size,
                              hipStream_t stream) {
  const float* x    = (const float*)d_in[0];
  const float* Wq   = (const float*)d_in[1];
  const float* Wk   = (const float*)d_in[2];
  const float* Wv   = (const float*)d_in[3];
  const float* Wo   = (const float*)d_in[4];
  const float* Wup  = (const float*)d_in[5];
  const float* Wdn  = (const float*)d_in[6];
  const float* ln1m = (const float*)d_in[7];
  const float* ln1s = (const float*)d_in[8];
  const float* ln2m = (const float*)d_in[9];
  const float* ln2s = (const float*)d_in[10];
  float* out = (float*)d_out;

  unsigned short* ws = (unsigned short*)d_ws;
  size_t off = 0;
  unsigned short* wqkv = ws + off; off += (size_t)3072 * 1024;
  unsigned short* wo   = ws + off; off += (size_t)1024 * 1024;
  unsigned short* wup  = ws + off; off += (size_t)4096 * 1024;
  unsigned short* wdn  = ws + off; off += (size_t)1024 * 4096;
  unsigned short* xln  = ws + off; off += (size_t)NTOK * 1024;
  unsigned short* qkvb = ws + off; off += (size_t)NTOK * 3072;
  unsigned short* pre  = ws + off; off += (size_t)NTOK * 1024;
  unsigned short* mid  = qkvb;   // up-GEMM out [4096][4096] spans qkvb+pre exactly
  unsigned short* vtg  = xln;    // V^T aliases xln during attention (dead until LN2)
  unsigned short* po0  = qkvb;   // O-proj partials (qkvb dead after attn)
  unsigned short* po1  = qkvb + (size_t)NTOK * 1024;
  unsigned short* pd0  = ws;     // down partial 0: wqkv+wo region (weights dead)
  unsigned short* pd1  = xln;    // down partial 1 (NOT pre: pre aliases mid rows)
  // attention split-key scratch:
  unsigned short* ap1  = (unsigned short*)out;     // partial O (z=1); out dead until reduce_ln
  float* al0 = (float*)wqkv;                       // row-sums: wqkv region dead after QKV gemm
  float* al1 = al0 + (size_t)2 * NH * SEQ;

  // fused weight casts (12288 blocks x 1024 elems)
  cast6_kernel<<<12288, 256, 0, stream>>>(Wq, Wk, Wv, Wo, Wup, Wdn,
      wqkv, wqkv + (size_t)1024 * 1024, wqkv + (size_t)2 * 1024 * 1024, wo, wup, wdn);

  // LN1
  ln_kernel<<<NTOK, 256, 0, stream>>>(x, ln1m, ln1s, xln);
  // fused QKV projection (wqkv consumed here; its region is scratch afterwards)
  gemm_nt<0><<<dim3(24, 32, 1), 256, 0, stream>>>(xln, wqkv, 3072, 1024, 1024, qkvb, nullptr);
  // V transpose (xln region becomes vtg)
  vtrans_kernel<<<dim3(32, 32), 256, 0, stream>>>(qkvb, vtg);
  // causal flash attention, split-key z=2, XCD-swizzled grid (bh fastest)
  attn_kernel<<<dim3(2 * NH, SEQ / 64, 2), 256, 0, stream>>>(qkvb, vtg, pre, ap1, al0, al1);
  // combine: pre = (pre + ap1) / (al0 + al1)
  attn_combine_kernel<<<4096, 256, 0, stream>>>(pre, ap1, al0, al1);
  // O-projection, split-K=2 -> bf16 partials
  gemm_nt<0><<<dim3(8, 32, 2), 256, 0, stream>>>(pre, wo, 1024, 1024, 512, po0, po1);
  // fused: out = x + po0 + po1 ; xln = LN2(out)
  reduce_ln_kernel<<<NTOK, 256, 0, stream>>>(po0, po1, x, ln2m, ln2s, out, xln);
  // MLP up + exact GELU -> mid
  gemm_nt<2><<<dim3(32, 32, 1), 256, 0, stream>>>(xln, wup, 4096, 1024, 1024, mid, nullptr);
  // MLP down, split-K=2 -> bf16 partials (pd1 = xln, no overlap with mid)
  gemm_nt<0><<<dim3(8, 32, 2), 256, 0, stream>>>(mid, wdn, 1024, 4096, 2048, pd0, pd1);
  // out += pd0 + pd1
  reduce2_kernel<<<4096, 256, 0, stream>>>(pd0, pd1, out);
}